// Round 3
// baseline (1039.441 us; speedup 1.0000x reference)
//
#include <hip/hip_runtime.h>

// SGC: out = A_hat^2 (x W^T) + b,  A_hat = D^-1/2 (A+I) D^-1/2.
// g-carry trick: g = D^-1/2 h, so each hop is an UNWEIGHTED neighbor sum:
//   g0 = dinv .* (x W^T)
//   g1 = dinv^2 .* (g0 + sum_{dst=n} g0[src])
//   out = dinv .* (g1 + sum_{dst=n} g1[src]) + b
// Edges are binned once into 128-node dst-buckets (packed u32: row7|src17),
// hops accumulate in a 32KB LDS tile per bucket -> zero global atomics in hops,
// fully coalesced output writes, no CSR/scan/fill.
//
// ws (4B elems): ideg[N] | gcur[NBP] | pairs[NBP*CAP] | g1[N*64]  (~34 MB)

#define DF 64
#define BSHIFT 7
#define BNODES 128                 // nodes per bucket
#define NBP 1024                   // padded bucket count (used: ceil(N/128)=782)
#define CAP 2048                   // pair capacity per bucket (avg 1279, +21 sigma)
#define CHUNK 8192                 // edges per binning chunk

// ---- init: ideg=0, bucket cursors = region base ----
__global__ __launch_bounds__(256) void zero_k(int* __restrict__ ideg,
                                              int* __restrict__ gcur, int n) {
    int i = blockIdx.x * 256 + threadIdx.x;
    if (i < n) ideg[i] = 0;
    if (i < NBP) gcur[i] = i * CAP;
}

// ---- chunked counting-sort of edges into dst-buckets + degree count ----
// One block per 8192-edge chunk: LDS count -> block scan -> ONE global
// reservation per (chunk,bucket) -> contiguous run writes (no line bouncing).
__global__ __launch_bounds__(256) void bucket_k(const int* __restrict__ src,
                                                const int* __restrict__ dst,
                                                int* ideg, int* gcur,
                                                unsigned* __restrict__ pairs, int ne) {
    __shared__ int bcnt[NBP];
    __shared__ int bofs[NBP];      // exclusive offsets, then running cursor
    __shared__ int gshift[NBP];    // global_base - local_exclusive_base
    __shared__ int stmp[256];
    int t = threadIdx.x;
    int e0 = blockIdx.x * CHUNK;
    int ecnt = min(CHUNK, ne - e0);

    for (int b = t; b < NBP; b += 256) bcnt[b] = 0;
    __syncthreads();

    // pass 1: per-bucket counts + global degree
    for (int i = t; i < ecnt; i += 256) {
        int d = dst[e0 + i];
        atomicAdd(&bcnt[d >> BSHIFT], 1);
        atomicAdd(&ideg[d], 1);
    }
    __syncthreads();

    // block-exclusive scan over NBP=1024 counts (thread t owns 4t..4t+3)
    int b4 = t * 4;
    int c0 = bcnt[b4], c1 = bcnt[b4 + 1], c2 = bcnt[b4 + 2], c3 = bcnt[b4 + 3];
    int tsum = c0 + c1 + c2 + c3;
    stmp[t] = tsum;
    __syncthreads();
    for (int off = 1; off < 256; off <<= 1) {
        int v = stmp[t];
        int u = (t >= off) ? stmp[t - off] : 0;
        __syncthreads();
        stmp[t] = v + u;
        __syncthreads();
    }
    int ex = stmp[t] - tsum;
    int e1 = ex + c0, e2 = e1 + c1, e3 = e2 + c2;
    bofs[b4] = ex; bofs[b4 + 1] = e1; bofs[b4 + 2] = e2; bofs[b4 + 3] = e3;
    // bulk-reserve global runs (one atomic per non-empty bucket per chunk)
    if (c0 > 0) gshift[b4]     = atomicAdd(&gcur[b4],     c0) - ex;
    if (c1 > 0) gshift[b4 + 1] = atomicAdd(&gcur[b4 + 1], c1) - e1;
    if (c2 > 0) gshift[b4 + 2] = atomicAdd(&gcur[b4 + 2], c2) - e2;
    if (c3 > 0) gshift[b4 + 3] = atomicAdd(&gcur[b4 + 3], c3) - e3;
    __syncthreads();

    // pass 2: scatter packed entries into contiguous per-bucket runs
    for (int i = t; i < ecnt; i += 256) {
        int d = dst[e0 + i], s = src[e0 + i];
        int b = d >> BSHIFT;
        int lp = atomicAdd(&bofs[b], 1);
        pairs[gshift[b] + lp] = ((unsigned)(d & (BNODES - 1)) << 17) | (unsigned)s;
    }
}

// ---- g0 = dinv .* (x W^T): wave per row, W[j][:] in lane-j registers ----
__global__ __launch_bounds__(256) void gemm_xw(const float* __restrict__ x,
                                               const float* __restrict__ Wm,
                                               const int* __restrict__ ideg,
                                               float* __restrict__ g0, int nrows) {
    int lane = threadIdx.x & 63;
    int wave = (blockIdx.x * blockDim.x + threadIdx.x) >> 6;
    int nwaves = (gridDim.x * blockDim.x) >> 6;

    float w[DF];
#pragma unroll
    for (int k = 0; k < DF; ++k) w[k] = Wm[lane * DF + k];

    for (int r = wave; r < nrows; r += nwaves) {
        float hv = x[r * DF + lane];
        float dv = rsqrtf((float)(1 + ideg[r]));
        float a0 = 0.f, a1 = 0.f, a2 = 0.f, a3 = 0.f;
#pragma unroll
        for (int k = 0; k < DF; k += 4) {
            float x0 = __uint_as_float(__builtin_amdgcn_readlane(__float_as_uint(hv), k + 0));
            float x1 = __uint_as_float(__builtin_amdgcn_readlane(__float_as_uint(hv), k + 1));
            float x2 = __uint_as_float(__builtin_amdgcn_readlane(__float_as_uint(hv), k + 2));
            float x3 = __uint_as_float(__builtin_amdgcn_readlane(__float_as_uint(hv), k + 3));
            a0 = fmaf(x0, w[k + 0], a0);
            a1 = fmaf(x1, w[k + 1], a1);
            a2 = fmaf(x2, w[k + 2], a2);
            a3 = fmaf(x3, w[k + 3], a3);
        }
        g0[r * DF + lane] = dv * ((a0 + a1) + (a2 + a3));
    }
}

// ---- hop: one bucket per block, LDS accumulate, coalesced epilogue ----
// MODE 0: out = dinv^2*(acc+self)        MODE 1: out = dinv*(acc+self)+bias
template <int MODE>
__global__ __launch_bounds__(512) void hop_k(const int* __restrict__ gcur,
                                             const unsigned* __restrict__ pairs,
                                             const int* __restrict__ ideg,
                                             const float* __restrict__ gin,
                                             const float* __restrict__ bias,
                                             float* __restrict__ out, int n) {
    __shared__ float acc[BNODES * DF];   // 32 KB
    int t = threadIdx.x;
    int lane = t & 63;
    int b = blockIdx.x;
    int node0 = b << BSHIFT;

    for (int i = t; i < BNODES * DF; i += 512) acc[i] = 0.f;
    __syncthreads();

    int base = b * CAP;
    int size = min(gcur[b] - base, CAP);
    int wid = __builtin_amdgcn_readfirstlane(t >> 6);   // 0..7, wave-uniform

    int i = wid;
    for (; i + 24 < size; i += 32) {                    // 8 waves x 4-deep ILP
        unsigned p0 = pairs[base + i];
        unsigned p1 = pairs[base + i + 8];
        unsigned p2 = pairs[base + i + 16];
        unsigned p3 = pairs[base + i + 24];
        float v0 = gin[(p0 & 0x1FFFF) * DF + lane];
        float v1 = gin[(p1 & 0x1FFFF) * DF + lane];
        float v2 = gin[(p2 & 0x1FFFF) * DF + lane];
        float v3 = gin[(p3 & 0x1FFFF) * DF + lane];
        atomicAdd(&acc[(p0 >> 17) * DF + lane], v0);
        atomicAdd(&acc[(p1 >> 17) * DF + lane], v1);
        atomicAdd(&acc[(p2 >> 17) * DF + lane], v2);
        atomicAdd(&acc[(p3 >> 17) * DF + lane], v3);
    }
    for (; i < size; i += 8) {
        unsigned p = pairs[base + i];
        float v = gin[(p & 0x1FFFF) * DF + lane];
        atomicAdd(&acc[(p >> 17) * DF + lane], v);
    }
    __syncthreads();

    int nn = min(BNODES, n - node0);
    for (int r = wid; r < nn; r += 8) {
        int nd = node0 + r;
        float dv = rsqrtf((float)(1 + ideg[nd]));
        float a = acc[r * DF + lane] + gin[nd * DF + lane];   // + self-loop
        if (MODE == 0) out[nd * DF + lane] = dv * dv * a;
        else           out[nd * DF + lane] = fmaf(dv, a, bias[lane]);
    }
}

extern "C" void kernel_launch(void* const* d_in, const int* in_sizes, int n_in,
                              void* d_out, int out_size, void* d_ws, size_t ws_size,
                              hipStream_t stream) {
    const float* x  = (const float*)d_in[0];
    const int*   ei = (const int*)d_in[1];
    const float* Wm = (const float*)d_in[2];
    const float* b  = (const float*)d_in[3];

    const int N = in_sizes[0] / DF;   // 100000
    const int E = in_sizes[1] / 2;    // 1000000
    const int* src = ei;
    const int* dst = ei + E;

    int*      ideg  = (int*)d_ws;                  // N
    int*      gcur  = ideg + N;                    // NBP
    unsigned* pairs = (unsigned*)(gcur + NBP);     // NBP*CAP  (8 MB)
    float*    g1    = (float*)(pairs + NBP * CAP); // N*DF
    float*    g0    = (float*)d_out;               // reuse output buffer

    const int BT = 256;
    int gZ  = (max(N, NBP) + BT - 1) / BT;
    int gC  = (E + CHUNK - 1) / CHUNK;             // 123 chunks
    int NB  = (N + BNODES - 1) / BNODES;           // 782 buckets

    zero_k<<<gZ, BT, 0, stream>>>(ideg, gcur, N);
    bucket_k<<<gC, BT, 0, stream>>>(src, dst, ideg, gcur, pairs, E);
    gemm_xw<<<1024, BT, 0, stream>>>(x, Wm, ideg, g0, N);
    hop_k<0><<<NB, 512, 0, stream>>>(gcur, pairs, ideg, g0, nullptr, g1, N);
    hop_k<1><<<NB, 512, 0, stream>>>(gcur, pairs, ideg, g1, b, g0, N);
}

// Round 4
// 234.621 us; speedup vs baseline: 4.4303x; 4.4303x over previous
//
#include <hip/hip_runtime.h>

// SGC: out = A_hat^2 (x W^T) + b,  A_hat = D^-1/2 (A+I) D^-1/2.
// g-carry trick: g = D^-1/2 h, so each hop is an UNWEIGHTED neighbor sum:
//   g0 = dinv .* (x W^T)
//   g1 = dinv^2 .* (g0 + sum_{dst=n} g0[src])
//   out = dinv .* (g1 + sum_{dst=n} g1[src]) + b
//
// CSR build without global scans or random 4B scatters:
//   bucket_k : chunked counting-sort of edges into 782 dst-buckets (128 nodes
//              each) -> contiguous per-(chunk,bucket) runs, 1 atomic per run.
//   regroup_k: per bucket, LDS histogram + scan + scatter -> per-node runs,
//              written back IN-PLACE (coalesced); meta[node] = {beg, cnt}.
//              Degree = cnt (free), dinv computed on the fly.
// Hops: R2's proven shape — one wave per node, register accumulation, 100k
// independent waves for max TLP; 8-deep ILP chains.
//
// ws: gcur[1024] | pairs/ent[1024*2048] (8MB, in-place) | meta int2[N] | g1[N*64]

#define DF 64
#define BSHIFT 7
#define BNODES 128                 // nodes per bucket
#define NBP 1024                   // padded bucket count (used: ceil(N/128)=782)
#define CAP 2048                   // entries per bucket region (avg 1279, +21 sigma)
#define CHUNK 8192                 // edges per binning chunk

// ---- init bucket cursors ----
__global__ __launch_bounds__(256) void zero_k(int* __restrict__ gcur) {
    int i = blockIdx.x * 256 + threadIdx.x;
    if (i < NBP) gcur[i] = i * CAP;
}

// ---- chunked counting-sort of edges into dst-buckets ----
__global__ __launch_bounds__(256) void bucket_k(const int* __restrict__ src,
                                                const int* __restrict__ dst,
                                                int* gcur,
                                                unsigned* __restrict__ pairs, int ne) {
    __shared__ int bcnt[NBP];
    __shared__ int bofs[NBP];      // exclusive offsets, then running cursor
    __shared__ int gshift[NBP];    // global_base - local_exclusive_base
    __shared__ int stmp[256];
    int t = threadIdx.x;
    int e0 = blockIdx.x * CHUNK;
    int ecnt = min(CHUNK, ne - e0);

    for (int b = t; b < NBP; b += 256) bcnt[b] = 0;
    __syncthreads();

    // pass 1: per-bucket counts
    for (int i = t; i < ecnt; i += 256) {
        int d = dst[e0 + i];
        atomicAdd(&bcnt[d >> BSHIFT], 1);
    }
    __syncthreads();

    // block-exclusive scan over NBP=1024 counts (thread t owns 4t..4t+3)
    int b4 = t * 4;
    int c0 = bcnt[b4], c1 = bcnt[b4 + 1], c2 = bcnt[b4 + 2], c3 = bcnt[b4 + 3];
    int tsum = c0 + c1 + c2 + c3;
    stmp[t] = tsum;
    __syncthreads();
    for (int off = 1; off < 256; off <<= 1) {
        int v = stmp[t];
        int u = (t >= off) ? stmp[t - off] : 0;
        __syncthreads();
        stmp[t] = v + u;
        __syncthreads();
    }
    int ex = stmp[t] - tsum;
    int e1 = ex + c0, e2 = e1 + c1, e3 = e2 + c2;
    bofs[b4] = ex; bofs[b4 + 1] = e1; bofs[b4 + 2] = e2; bofs[b4 + 3] = e3;
    if (c0 > 0) gshift[b4]     = atomicAdd(&gcur[b4],     c0) - ex;
    if (c1 > 0) gshift[b4 + 1] = atomicAdd(&gcur[b4 + 1], c1) - e1;
    if (c2 > 0) gshift[b4 + 2] = atomicAdd(&gcur[b4 + 2], c2) - e2;
    if (c3 > 0) gshift[b4 + 3] = atomicAdd(&gcur[b4 + 3], c3) - e3;
    __syncthreads();

    // pass 2: scatter packed entries (row7|src17) into contiguous runs
    for (int i = t; i < ecnt; i += 256) {
        int d = dst[e0 + i], s = src[e0 + i];
        int b = d >> BSHIFT;
        int lp = atomicAdd(&bofs[b], 1);
        pairs[gshift[b] + lp] = ((unsigned)(d & (BNODES - 1)) << 17) | (unsigned)s;
    }
}

// ---- per-bucket regroup: node-sorted entries (in-place) + meta{beg,cnt} ----
__global__ __launch_bounds__(256) void regroup_k(const int* __restrict__ gcur,
                                                 unsigned* pairs,   // in: packed, out: ent
                                                 int2* __restrict__ meta, int n) {
    __shared__ int hist[BNODES];
    __shared__ int cur[BNODES];
    __shared__ int stage[CAP];
    int t = threadIdx.x, b = blockIdx.x;
    int base = b * CAP;
    int size = min(gcur[b] - base, CAP);

    if (t < BNODES) hist[t] = 0;
    __syncthreads();

    for (int i = t; i < size; i += 256)
        atomicAdd(&hist[pairs[base + i] >> 17], 1);
    __syncthreads();

    int cnt = (t < BNODES) ? hist[t] : 0;
    // Hillis-Steele inclusive scan over hist[0..127]
    for (int off = 1; off < BNODES; off <<= 1) {
        int u = (t < BNODES && t >= off) ? hist[t - off] : 0;
        __syncthreads();
        if (t < BNODES) hist[t] += u;
        __syncthreads();
    }
    if (t < BNODES) {
        int ex = hist[t] - cnt;
        cur[t] = ex;
        int node = (b << BSHIFT) + t;
        if (node < n) meta[node] = make_int2(base + ex, cnt);
    }
    __syncthreads();

    // scatter into LDS stage grouped by node
    for (int i = t; i < size; i += 256) {
        unsigned p = pairs[base + i];
        int pos = atomicAdd(&cur[p >> 17], 1);
        stage[pos] = (int)(p & 0x1FFFF);
    }
    __syncthreads();

    // coalesced write-back over the same region (block exclusively owns it)
    for (int i = t; i < size; i += 256)
        pairs[base + i] = (unsigned)stage[i];
}

// ---- g0 = dinv .* (x W^T): wave per row, W[j][:] in lane-j registers ----
__global__ __launch_bounds__(256) void gemm_xw(const float* __restrict__ x,
                                               const float* __restrict__ Wm,
                                               const int2* __restrict__ meta,
                                               float* __restrict__ g0, int nrows) {
    int lane = threadIdx.x & 63;
    int wave = (blockIdx.x * blockDim.x + threadIdx.x) >> 6;
    int nwaves = (gridDim.x * blockDim.x) >> 6;

    float w[DF];
#pragma unroll
    for (int k = 0; k < DF; ++k) w[k] = Wm[lane * DF + k];

    for (int r = wave; r < nrows; r += nwaves) {
        float hv = x[r * DF + lane];
        float dv = rsqrtf((float)(1 + meta[r].y));
        float a0 = 0.f, a1 = 0.f, a2 = 0.f, a3 = 0.f;
#pragma unroll
        for (int k = 0; k < DF; k += 4) {
            float x0 = __uint_as_float(__builtin_amdgcn_readlane(__float_as_uint(hv), k + 0));
            float x1 = __uint_as_float(__builtin_amdgcn_readlane(__float_as_uint(hv), k + 1));
            float x2 = __uint_as_float(__builtin_amdgcn_readlane(__float_as_uint(hv), k + 2));
            float x3 = __uint_as_float(__builtin_amdgcn_readlane(__float_as_uint(hv), k + 3));
            a0 = fmaf(x0, w[k + 0], a0);
            a1 = fmaf(x1, w[k + 1], a1);
            a2 = fmaf(x2, w[k + 2], a2);
            a3 = fmaf(x3, w[k + 3], a3);
        }
        g0[r * DF + lane] = dv * ((a0 + a1) + (a2 + a3));
    }
}

// ---- gather hop: one wave per node, register accumulation, 8-deep ILP ----
// MODE 0: out = dinv^2*(self+acc)      MODE 1: out = dinv*(self+acc)+bias
template <int MODE>
__global__ __launch_bounds__(256) void gather_k(const int2* __restrict__ meta,
                                                const unsigned* __restrict__ ent,
                                                const float* __restrict__ gin,
                                                const float* __restrict__ bias,
                                                float* __restrict__ out, int n) {
    int lane = threadIdx.x & 63;
    int wid = (blockIdx.x * blockDim.x + threadIdx.x) >> 6;
    wid = __builtin_amdgcn_readfirstlane(wid);   // wave-uniform -> scalar loads
    if (wid >= n) return;

    int2 m = meta[wid];
    int beg = m.x, cnt = m.y;
    float dv = rsqrtf((float)(1 + cnt));

    float a0 = gin[wid * DF + lane];  // self-loop term
    float a1 = 0.f, a2 = 0.f, a3 = 0.f, a4 = 0.f, a5 = 0.f, a6 = 0.f, a7 = 0.f;

    int i = beg, end = beg + cnt;
    for (; i + 7 < end; i += 8) {     // 8 independent chains
        int s0 = ent[i + 0], s1 = ent[i + 1], s2 = ent[i + 2], s3 = ent[i + 3];
        int s4 = ent[i + 4], s5 = ent[i + 5], s6 = ent[i + 6], s7 = ent[i + 7];
        a0 += gin[s0 * DF + lane];
        a1 += gin[s1 * DF + lane];
        a2 += gin[s2 * DF + lane];
        a3 += gin[s3 * DF + lane];
        a4 += gin[s4 * DF + lane];
        a5 += gin[s5 * DF + lane];
        a6 += gin[s6 * DF + lane];
        a7 += gin[s7 * DF + lane];
    }
    for (; i + 3 < end; i += 4) {
        int s0 = ent[i + 0], s1 = ent[i + 1], s2 = ent[i + 2], s3 = ent[i + 3];
        a0 += gin[s0 * DF + lane];
        a1 += gin[s1 * DF + lane];
        a2 += gin[s2 * DF + lane];
        a3 += gin[s3 * DF + lane];
    }
    for (; i < end; ++i) a0 += gin[ent[i] * DF + lane];

    float acc = ((a0 + a1) + (a2 + a3)) + ((a4 + a5) + (a6 + a7));
    if (MODE == 0)
        out[wid * DF + lane] = dv * dv * acc;
    else
        out[wid * DF + lane] = fmaf(dv, acc, bias[lane]);
}

extern "C" void kernel_launch(void* const* d_in, const int* in_sizes, int n_in,
                              void* d_out, int out_size, void* d_ws, size_t ws_size,
                              hipStream_t stream) {
    const float* x  = (const float*)d_in[0];
    const int*   ei = (const int*)d_in[1];
    const float* Wm = (const float*)d_in[2];
    const float* b  = (const float*)d_in[3];

    const int N = in_sizes[0] / DF;   // 100000
    const int E = in_sizes[1] / 2;    // 1000000
    const int* src = ei;
    const int* dst = ei + E;

    int*      gcur  = (int*)d_ws;                    // NBP
    unsigned* pairs = (unsigned*)(gcur + NBP);       // NBP*CAP (8MB), becomes ent
    int2*     meta  = (int2*)(pairs + NBP * CAP);    // N
    float*    g1    = (float*)(meta + N);            // N*DF
    float*    g0    = (float*)d_out;                 // reuse output buffer

    int gC = (E + CHUNK - 1) / CHUNK;                // 123 chunks
    int NB = (N + BNODES - 1) / BNODES;              // 782 buckets
    int gG = (N * DF + 255) / 256;                   // one wave per node

    zero_k<<<4, 256, 0, stream>>>(gcur);
    bucket_k<<<gC, 256, 0, stream>>>(src, dst, gcur, pairs, E);
    regroup_k<<<NB, 256, 0, stream>>>(gcur, pairs, meta, N);
    gemm_xw<<<1024, 256, 0, stream>>>(x, Wm, meta, g0, N);
    gather_k<0><<<gG, 256, 0, stream>>>(meta, pairs, g0, nullptr, g1, N);
    gather_k<1><<<gG, 256, 0, stream>>>(meta, pairs, g1, b, g0, N);
}